// Round 11
// baseline (438.504 us; speedup 1.0000x reference)
//
#include <hip/hip_runtime.h>

#define N_DATA     131072
#define D_VECTOR   128
#define N_SUB      8
#define D_SUB      16
#define N_CLUSTERS 256
#define N_CODEBOOKS 64

typedef float v2f __attribute__((ext_vector_type(2)));

// ws layout in 4-byte words (~2.5 MB base; +8 MB optional cbT2 if ws permits).
// xg[s][dst][16] (permuted-gathered x, 64 MiB) lives in d_out until decode
// overwrites it.
#define WS_LABELS 0
#define WS_PERM   (N_DATA)
#define WS_CNT    (2*N_DATA)
#define WS_CURSOR (2*N_DATA + 64)
#define WS_OFF    (2*N_DATA + 128)
#define WS_CNORM  (2*N_DATA + 256)                  // 512 rows x 256 k, numpy-order fp32
#define WS_CNSEL  (WS_CNORM + N_CODEBOOKS*N_SUB*N_CLUSTERS)
#define WS_CODES  (WS_CNSEL + 64)                   // 131072*8 bytes = 262144 words
#define WS_CBT2   (WS_CODES + 262144)               // optional: row-major codebook for decode
#define CBT2_WORDS (N_CODEBOOKS*N_SUB*N_CLUSTERS*D_SUB)   // 2,097,152 words = 8 MiB

// ---------------------------------------------------------------- precompute
// cnorm = np.sum(cb*cb, axis=2) (sequential d, separate mul/add). If cbT2 is
// non-null, also emit a row-major codebook cbT2[row][k][d] = cb[row][d][k]
// (row = l*8+s) so decode reads ONE 64B line per (point,s) instead of a
// 16-element strided column.
__global__ __launch_bounds__(256) void pq_precompute(
    const float* __restrict__ cb, const float* __restrict__ sel,
    float* __restrict__ cnorm_cb, float* __restrict__ cnorm_sel,
    float* __restrict__ cbT2, int* __restrict__ cnt)
{
    int row = blockIdx.x;                 // 0..511 = l*8+s
    int k   = threadIdx.x;                // 0..255
    const float* p = cb + (size_t)row * (D_SUB * N_CLUSTERS) + k;
    float vals[D_SUB];
    float sum = 0.f;
#pragma unroll
    for (int d = 0; d < D_SUB; d++) {
        float v = p[(size_t)d * N_CLUSTERS];
        vals[d] = v;
        sum = __fadd_rn(sum, __fmul_rn(v, v));
    }
    int idx = row * 256 + k;
    cnorm_cb[idx] = sum;
    if (cbT2) {                           // uniform branch
        float4* dst = (float4*)(cbT2 + ((size_t)row << 12) + ((size_t)k << 4));
#pragma unroll
        for (int q = 0; q < 4; q++)
            dst[q] = make_float4(vals[4*q], vals[4*q+1], vals[4*q+2], vals[4*q+3]);
    }
    if (idx < N_CODEBOOKS) {
        float s2 = 0.f;
        for (int d = 0; d < D_VECTOR; d++) {
            float v = sel[d * N_CODEBOOKS + idx];
            s2 = __fadd_rn(s2, __fmul_rn(v, v));
        }
        cnorm_sel[idx] = s2;
        cnt[idx] = 0;
    }
}

// ---------------------------------------------------------------- stage 1: labels
// d-loop unrolled x4: batches 4 coalesced x loads per group so HBM latency
// overlaps the pk-fma chain (acc[] pressure unchanged; xn chain stays
// sequential d -> numpy-exact).
__global__ __launch_bounds__(256, 4) void pq_labels2(
    const float* __restrict__ x, const float* __restrict__ sel,
    const float* __restrict__ cnorm_sel,
    int* __restrict__ labels, int* __restrict__ cnt)
{
    __shared__ int hist[N_CODEBOOKS];
    int tid = threadIdx.x;
    if (tid < N_CODEBOOKS) hist[tid] = 0;
    __syncthreads();

    int n = blockIdx.x * 256 + tid;

    v2f acc[32];
#pragma unroll
    for (int lp = 0; lp < 32; lp++) acc[lp] = (v2f){0.f, 0.f};

    float xn = 0.f;
#pragma unroll 4
    for (int d = 0; d < D_VECTOR; d++) {
        float xv = x[(size_t)d * N_DATA + n];        // coalesced
        xn = __fadd_rn(xn, __fmul_rn(xv, xv));       // sequential d: numpy-exact
        v2f xv2 = (v2f){xv, xv};
        const v2f* sp = (const v2f*)(sel + d * N_CODEBOOKS);  // uniform
#pragma unroll
        for (int lp = 0; lp < 32; lp++)
            acc[lp] = __builtin_elementwise_fma(xv2, sp[lp], acc[lp]);  // v_pk_fma_f32
    }

    float best = 1e30f;
    int   bl = 0;
#pragma unroll
    for (int lp = 0; lp < 32; lp++) {
        float dx = __fadd_rn(__fsub_rn(xn, __fmul_rn(2.0f, acc[lp].x)), cnorm_sel[2*lp]);
        float dy = __fadd_rn(__fsub_rn(xn, __fmul_rn(2.0f, acc[lp].y)), cnorm_sel[2*lp + 1]);
        if (dx < best) { best = dx; bl = 2*lp; }
        if (dy < best) { best = dy; bl = 2*lp + 1; }
    }
    labels[n] = bl;
    atomicAdd(&hist[bl], 1);
    __syncthreads();
    if (tid < N_CODEBOOKS) atomicAdd(&cnt[tid], hist[tid]);
}

// ---------------------------------------------------------------- scan (1 wave)
__global__ void pq_scan(const int* __restrict__ cnt, int* __restrict__ off, int* __restrict__ cursor)
{
    int tid = threadIdx.x;
    int v = cnt[tid];
    int inc = v;
#pragma unroll
    for (int sft = 1; sft < 64; sft <<= 1) {
        int o = __shfl_up(inc, sft, 64);
        if (tid >= sft) inc += o;
    }
    int exc = inc - v;
    off[tid] = exc;
    cursor[tid] = exc;
    if (tid == 63) off[64] = inc;
}

// ---------------------------------------------------------------- counting-sort scatter + permute-gather
// perm entries are PACKED: (n << 6) | label. Additionally copies each point's
// 8 subvectors into xg[s][dst][16] (exact fp32 copy): x reads are coalesced
// across threads (consecutive n), xg writes are dense scattered 64B lines.
// Encode then reads xg perfectly coalesced with zero gather.
__global__ __launch_bounds__(256) void pq_scatter(
    const float* __restrict__ x, const int* __restrict__ labels,
    int* __restrict__ cursor, unsigned int* __restrict__ perm,
    float* __restrict__ xg)
{
    __shared__ int lcnt[N_CODEBOOKS];
    __shared__ int lbase[N_CODEBOOKS];
    int tid = threadIdx.x;
    if (tid < N_CODEBOOKS) lcnt[tid] = 0;
    __syncthreads();
    int base = blockIdx.x * 1024;
    int lv[4], slot[4];
#pragma unroll
    for (int i = 0; i < 4; i++) {
        int n = base + i * 256 + tid;
        int l = labels[n];
        lv[i] = l;
        slot[i] = atomicAdd(&lcnt[l], 1);
    }
    __syncthreads();
    if (tid < N_CODEBOOKS) lbase[tid] = atomicAdd(&cursor[tid], lcnt[tid]);
    __syncthreads();
#pragma unroll
    for (int i = 0; i < 4; i++) {
        int n = base + i * 256 + tid;
        int dst = lbase[lv[i]] + slot[i];
        perm[dst] = ((unsigned)n << 6) | (unsigned)lv[i];
#pragma unroll
        for (int s = 0; s < N_SUB; s++) {
            float v[D_SUB];
#pragma unroll
            for (int d = 0; d < D_SUB; d++)
                v[d] = x[(size_t)(s * D_SUB + d) * N_DATA + n];   // coalesced
            float4* o = (float4*)(xg + (((size_t)s * N_DATA + (size_t)dst) << 4));
            o[0] = make_float4(v[0],  v[1],  v[2],  v[3]);
            o[1] = make_float4(v[4],  v[5],  v[6],  v[7]);
            o[2] = make_float4(v[8],  v[9],  v[10], v[11]);
            o[3] = make_float4(v[12], v[13], v[14], v[15]);
        }
    }
}

// ---------------------------------------------------------------- stage 2: PQ encode (v8 structure)
// Lane = one point, in perm order: x reads from xg are fully coalesced.
// Codebook is streamed straight from cb via wave-uniform scalar loads.
// Boundary waves (~3%) use the ballot multipass. Arithmetic per (point,k)
// unchanged: sequential-d separate mul/add (contract off),
// dist = (xn - 2*acc) + cn. Argmin: per-component chains (even/odd k),
// ascending kkp strict <, merged with the exact lower-k tie rule -> numpy
// first-occurrence. Distances NaN-free.
// Schedule: kkp loop unroll 8 (4 was +22us over 2; SGPR headroom 80->102+,
// no vector-typed staging arrays -> no v9-style spill path).
__global__ __launch_bounds__(256, 8) void pq_encode9(
    const float* __restrict__ xg, const float* __restrict__ cb,
    const float* __restrict__ cnorm_cb, const unsigned int* __restrict__ perm,
    unsigned char* __restrict__ codes)
{
    int tid = threadIdx.x;
    int s   = blockIdx.x & 7;
    int pos = (int)(blockIdx.x >> 3) * 256 + tid;
    unsigned pk = perm[pos];
    int n = (int)(pk >> 6);
    int l = (int)(pk & 63u);

    const float4* xp = (const float4*)(xg + (((size_t)s * N_DATA + (size_t)pos) << 4));
    float4 x0 = xp[0], x1 = xp[1], x2 = xp[2], x3 = xp[3];
    float xs[D_SUB] = { x0.x, x0.y, x0.z, x0.w, x1.x, x1.y, x1.z, x1.w,
                        x2.x, x2.y, x2.z, x2.w, x3.x, x3.y, x3.z, x3.w };

    // xnorm: numpy strided reduction (sequential d, separate mul/add)
    float xn = 0.f;
#pragma unroll
    for (int d = 0; d < D_SUB; d++)
        xn = __fadd_rn(xn, __fmul_rn(xs[d], xs[d]));

    v2f xs2[D_SUB];
#pragma unroll
    for (int d = 0; d < D_SUB; d++) xs2[d] = (v2f){xs[d], xs[d]};
    const v2f xnv  = (v2f){xn, xn};
    const v2f twov = (v2f){2.f, 2.f};

    int bestk = 0;
    bool done = false;
    while (true) {
        unsigned long long todo = __ballot(!done);
        if (!todo) break;
        int src  = (int)(__ffsll((long long)todo) - 1);
        int lcur = __builtin_amdgcn_readlane(l, src);      // uniform label for this pass

        const float* cbs = cb       + ((size_t)(lcur * N_SUB + s) << 12);  // [d][k] row -> s_load
        const float* cns = cnorm_cb + ((size_t)(lcur * N_SUB + s) << 8);   // uniform -> s_load

        float bx = 1e30f, by = 1e30f;
        int   kx = 0, ky = 0;
        {
#pragma clang fp contract(off)
#pragma unroll 8
            for (int kkp = 0; kkp < N_CLUSTERS / 2; kkp++) {
                v2f cn2 = *(const v2f*)(cns + (kkp << 1));
                v2f a = (v2f){0.f, 0.f};
#pragma unroll
                for (int d = 0; d < D_SUB; d++) {
                    v2f c = *(const v2f*)(cbs + (size_t)(d * N_CLUSTERS) + (kkp << 1));
                    a = a + xs2[d] * c;          // v_pk_mul + v_pk_add, exact order
                }
                v2f dd = (xnv - twov * a) + cn2;
                if (dd.x < bx) { bx = dd.x; kx = kkp; }
                if (dd.y < by) { by = dd.y; ky = kkp; }
            }
        }
        // merge even/odd chains: strictly-better or equal-with-lower-k picks odd
        int bk = 2 * kx;
        { int kodd = 2 * ky + 1; if (by < bx || (by == bx && kodd < bk)) bk = kodd; }

        if (!done && l == lcur) { bestk = bk; done = true; }
    }
    codes[((size_t)n << 3) | s] = (unsigned char)bestk;
}

// ---------------------------------------------------------------- decode (fast): 1 line per (n,s)
__global__ __launch_bounds__(256) void pq_decode_fast(
    const float* __restrict__ cbT2, const int* __restrict__ labels,
    const unsigned char* __restrict__ codes, float* __restrict__ out)
{
    int s = blockIdx.x & 7;
    int n = (blockIdx.x >> 3) * 256 + threadIdx.x;
    int l = labels[n];
    int k = codes[(size_t)n * N_SUB + s];
    const float4* p = (const float4*)(cbT2 + ((size_t)(l * N_SUB + s) << 12) + ((size_t)k << 4));
    float4 a = p[0], b = p[1], c = p[2], d = p[3];
    float v[D_SUB] = { a.x, a.y, a.z, a.w, b.x, b.y, b.z, b.w,
                       c.x, c.y, c.z, c.w, d.x, d.y, d.z, d.w };
#pragma unroll
    for (int dd = 0; dd < D_SUB; dd++)
        out[(size_t)(s * D_SUB + dd) * N_DATA + n] = v[dd];   // coalesced
}

// ---------------------------------------------------------------- decode (fallback): strided column gather
__global__ __launch_bounds__(256) void pq_decode(
    const float* __restrict__ cb, const int* __restrict__ labels,
    const unsigned char* __restrict__ codes, float* __restrict__ out)
{
    int s = blockIdx.x & 7;
    int n = (blockIdx.x >> 3) * 256 + threadIdx.x;
    int l = labels[n];
    int k = codes[(size_t)n * N_SUB + s];
    const float* base = cb + ((size_t)(l * N_SUB + s) * D_SUB) * N_CLUSTERS + k;
#pragma unroll
    for (int dd = 0; dd < D_SUB; dd++)
        out[(size_t)(s * D_SUB + dd) * N_DATA + n] = base[(size_t)dd * N_CLUSTERS];
}

// ---------------------------------------------------------------- launcher
extern "C" void kernel_launch(void* const* d_in, const int* in_sizes, int n_in,
                              void* d_out, int out_size, void* d_ws, size_t ws_size,
                              hipStream_t stream)
{
    (void)in_sizes; (void)n_in; (void)out_size;
    const float* x   = (const float*)d_in[0];
    const float* cb  = (const float*)d_in[1];
    const float* sel = (const float*)d_in[2];
    float* out = (float*)d_out;

    int*   wsi    = (int*)d_ws;
    float* wsf    = (float*)d_ws;
    int*   labels = wsi + WS_LABELS;
    unsigned int* perm = (unsigned int*)(wsi + WS_PERM);
    int*   cnt    = wsi + WS_CNT;
    int*   cursor = wsi + WS_CURSOR;
    int*   off    = wsi + WS_OFF;
    float* cnorm  = wsf + WS_CNORM;
    float* cnsel  = wsf + WS_CNSEL;
    unsigned char* codes = (unsigned char*)(wsi + WS_CODES);

    // row-major decode codebook only if the workspace is big enough (~10.5 MiB)
    bool big = ws_size >= (size_t)(WS_CBT2 + CBT2_WORDS) * 4u;
    float* cbT2 = big ? (wsf + WS_CBT2) : (float*)nullptr;

    // permuted-gathered x (64 MiB) lives in d_out; decode overwrites it fully
    float* xg = out;

    hipLaunchKernelGGL(pq_precompute, dim3(512), dim3(256), 0, stream, cb, sel, cnorm, cnsel, cbT2, cnt);
    hipLaunchKernelGGL(pq_labels2, dim3(N_DATA / 256), dim3(256), 0, stream, x, sel, cnsel, labels, cnt);
    hipLaunchKernelGGL(pq_scan, dim3(1), dim3(64), 0, stream, cnt, off, cursor);
    hipLaunchKernelGGL(pq_scatter, dim3(N_DATA / 1024), dim3(256), 0, stream, x, labels, cursor, perm, xg);
    hipLaunchKernelGGL(pq_encode9, dim3((N_DATA / 256) * N_SUB), dim3(256), 0, stream,
                       xg, cb, cnorm, perm, codes);
    if (big)
        hipLaunchKernelGGL(pq_decode_fast, dim3((N_DATA / 256) * N_SUB), dim3(256), 0, stream,
                           cbT2, labels, codes, out);
    else
        hipLaunchKernelGGL(pq_decode, dim3((N_DATA / 256) * N_SUB), dim3(256), 0, stream,
                           cb, labels, codes, out);
}

// Round 12
// 399.879 us; speedup vs baseline: 1.0966x; 1.0966x over previous
//
#include <hip/hip_runtime.h>

#define N_DATA     131072
#define D_VECTOR   128
#define N_SUB      8
#define D_SUB      16
#define N_CLUSTERS 256
#define N_CODEBOOKS 64

typedef float v2f __attribute__((ext_vector_type(2)));

// ws layout in 4-byte words (~2.5 MB base; +8 MB optional cbT2 if ws permits).
// xg[s][dst][16] (permuted-gathered x, 64 MiB) lives in d_out until decode
// overwrites it.
#define WS_LABELS 0
#define WS_PERM   (N_DATA)
#define WS_CNT    (2*N_DATA)
#define WS_CLAIM  (2*N_DATA + 64)
#define WS_CNORM  (2*N_DATA + 256)                  // 512 rows x 256 k, numpy-order fp32
#define WS_CNSEL  (WS_CNORM + N_CODEBOOKS*N_SUB*N_CLUSTERS)
#define WS_CODES  (WS_CNSEL + 64)                   // 131072*8 bytes = 262144 words
#define WS_CBT2   (WS_CODES + 262144)               // optional: row-major codebook for decode
#define CBT2_WORDS (N_CODEBOOKS*N_SUB*N_CLUSTERS*D_SUB)   // 2,097,152 words = 8 MiB

// ---------------------------------------------------------------- precompute
// cnorm = np.sum(cb*cb, axis=2) (sequential d, separate mul/add). If cbT2 is
// non-null, also emit a row-major codebook cbT2[row][k][d] = cb[row][d][k]
// (row = l*8+s) so decode reads ONE 64B line per (point,s) instead of a
// 16-element strided column. Also zero-inits cnt[] and claim[].
__global__ __launch_bounds__(256) void pq_precompute(
    const float* __restrict__ cb, const float* __restrict__ sel,
    float* __restrict__ cnorm_cb, float* __restrict__ cnorm_sel,
    float* __restrict__ cbT2, int* __restrict__ cnt, int* __restrict__ claim)
{
    int row = blockIdx.x;                 // 0..511 = l*8+s
    int k   = threadIdx.x;                // 0..255
    const float* p = cb + (size_t)row * (D_SUB * N_CLUSTERS) + k;
    float vals[D_SUB];
    float sum = 0.f;
#pragma unroll
    for (int d = 0; d < D_SUB; d++) {
        float v = p[(size_t)d * N_CLUSTERS];
        vals[d] = v;
        sum = __fadd_rn(sum, __fmul_rn(v, v));
    }
    int idx = row * 256 + k;
    cnorm_cb[idx] = sum;
    if (cbT2) {                           // uniform branch
        float4* dst = (float4*)(cbT2 + ((size_t)row << 12) + ((size_t)k << 4));
#pragma unroll
        for (int q = 0; q < 4; q++)
            dst[q] = make_float4(vals[4*q], vals[4*q+1], vals[4*q+2], vals[4*q+3]);
    }
    if (idx < N_CODEBOOKS) {
        float s2 = 0.f;
        for (int d = 0; d < D_VECTOR; d++) {
            float v = sel[d * N_CODEBOOKS + idx];
            s2 = __fadd_rn(s2, __fmul_rn(v, v));
        }
        cnorm_sel[idx] = s2;
        cnt[idx] = 0;
        claim[idx] = 0;
    }
}

// ---------------------------------------------------------------- stage 1: labels
// d-loop unrolled x4: batches 4 coalesced x loads per group so HBM latency
// overlaps the pk-fma chain (acc[] pressure unchanged; xn chain stays
// sequential d -> numpy-exact).
__global__ __launch_bounds__(256, 4) void pq_labels2(
    const float* __restrict__ x, const float* __restrict__ sel,
    const float* __restrict__ cnorm_sel,
    int* __restrict__ labels, int* __restrict__ cnt)
{
    __shared__ int hist[N_CODEBOOKS];
    int tid = threadIdx.x;
    if (tid < N_CODEBOOKS) hist[tid] = 0;
    __syncthreads();

    int n = blockIdx.x * 256 + tid;

    v2f acc[32];
#pragma unroll
    for (int lp = 0; lp < 32; lp++) acc[lp] = (v2f){0.f, 0.f};

    float xn = 0.f;
#pragma unroll 4
    for (int d = 0; d < D_VECTOR; d++) {
        float xv = x[(size_t)d * N_DATA + n];        // coalesced
        xn = __fadd_rn(xn, __fmul_rn(xv, xv));       // sequential d: numpy-exact
        v2f xv2 = (v2f){xv, xv};
        const v2f* sp = (const v2f*)(sel + d * N_CODEBOOKS);  // uniform
#pragma unroll
        for (int lp = 0; lp < 32; lp++)
            acc[lp] = __builtin_elementwise_fma(xv2, sp[lp], acc[lp]);  // v_pk_fma_f32
    }

    float best = 1e30f;
    int   bl = 0;
#pragma unroll
    for (int lp = 0; lp < 32; lp++) {
        float dx = __fadd_rn(__fsub_rn(xn, __fmul_rn(2.0f, acc[lp].x)), cnorm_sel[2*lp]);
        float dy = __fadd_rn(__fsub_rn(xn, __fmul_rn(2.0f, acc[lp].y)), cnorm_sel[2*lp + 1]);
        if (dx < best) { best = dx; bl = 2*lp; }
        if (dy < best) { best = dy; bl = 2*lp + 1; }
    }
    labels[n] = bl;
    atomicAdd(&hist[bl], 1);
    __syncthreads();
    if (tid < N_CODEBOOKS) atomicAdd(&cnt[tid], hist[tid]);
}

// ---------------------------------------------------------------- counting-sort scatter + permute-gather
// perm entries are PACKED: (n << 6) | label. The exclusive scan of cnt[] is
// recomputed locally per block (64-wide wave scan, ~100cy) and the cross-block
// cursor is claim[] (zero-init'd in precompute): dst = off[l] + claim-base +
// local slot. Replaces the separate pq_scan launch. Also copies each point's
// 8 subvectors into xg[s][dst][16]: x reads coalesced, xg writes dense 64B
// lines; encode then reads xg perfectly coalesced with zero gather.
__global__ __launch_bounds__(256) void pq_scatter(
    const float* __restrict__ x, const int* __restrict__ labels,
    const int* __restrict__ cnt, int* __restrict__ claim,
    unsigned int* __restrict__ perm, float* __restrict__ xg)
{
    __shared__ int lcnt[N_CODEBOOKS];
    __shared__ int loff[N_CODEBOOKS];
    __shared__ int lbase[N_CODEBOOKS];
    int tid = threadIdx.x;
    if (tid < N_CODEBOOKS) lcnt[tid] = 0;
    // wave 0 computes the exclusive scan of cnt[] into loff[]
    if (tid < 64) {
        int v = cnt[tid];
        int inc = v;
#pragma unroll
        for (int sft = 1; sft < 64; sft <<= 1) {
            int o = __shfl_up(inc, sft, 64);
            if (tid >= sft) inc += o;
        }
        loff[tid] = inc - v;
    }
    __syncthreads();
    int base = blockIdx.x * 1024;
    int lv[4], slot[4];
#pragma unroll
    for (int i = 0; i < 4; i++) {
        int n = base + i * 256 + tid;
        int l = labels[n];
        lv[i] = l;
        slot[i] = atomicAdd(&lcnt[l], 1);
    }
    __syncthreads();
    if (tid < N_CODEBOOKS)
        lbase[tid] = loff[tid] + atomicAdd(&claim[tid], lcnt[tid]);
    __syncthreads();
#pragma unroll
    for (int i = 0; i < 4; i++) {
        int n = base + i * 256 + tid;
        int dst = lbase[lv[i]] + slot[i];
        perm[dst] = ((unsigned)n << 6) | (unsigned)lv[i];
#pragma unroll
        for (int s = 0; s < N_SUB; s++) {
            float v[D_SUB];
#pragma unroll
            for (int d = 0; d < D_SUB; d++)
                v[d] = x[(size_t)(s * D_SUB + d) * N_DATA + n];   // coalesced
            float4* o = (float4*)(xg + (((size_t)s * N_DATA + (size_t)dst) << 4));
            o[0] = make_float4(v[0],  v[1],  v[2],  v[3]);
            o[1] = make_float4(v[4],  v[5],  v[6],  v[7]);
            o[2] = make_float4(v[8],  v[9],  v[10], v[11]);
            o[3] = make_float4(v[12], v[13], v[14], v[15]);
        }
    }
}

// ---------------------------------------------------------------- stage 2: PQ encode (v8 structure, proven 230us)
// Lane = one point, in perm order: x reads from xg are fully coalesced.
// Codebook is streamed straight from cb via wave-uniform scalar loads.
// Boundary waves (~3%) use the ballot multipass. Arithmetic per (point,k)
// unchanged: sequential-d separate mul/add (contract off),
// dist = (xn - 2*acc) + cn. Argmin: per-component chains (even/odd k),
// ascending kkp strict <, merged with the exact lower-k tie rule -> numpy
// first-occurrence. Distances NaN-free.
// Schedule: kkp loop unroll 4 — the measured optimum (2: 252us, 4: 230us,
// 8: 270us — past 4 the compiler re-rolls and keeps FEWER loads in flight).
__global__ __launch_bounds__(256, 8) void pq_encode9(
    const float* __restrict__ xg, const float* __restrict__ cb,
    const float* __restrict__ cnorm_cb, const unsigned int* __restrict__ perm,
    unsigned char* __restrict__ codes)
{
    int tid = threadIdx.x;
    int s   = blockIdx.x & 7;
    int pos = (int)(blockIdx.x >> 3) * 256 + tid;
    unsigned pk = perm[pos];
    int n = (int)(pk >> 6);
    int l = (int)(pk & 63u);

    const float4* xp = (const float4*)(xg + (((size_t)s * N_DATA + (size_t)pos) << 4));
    float4 x0 = xp[0], x1 = xp[1], x2 = xp[2], x3 = xp[3];
    float xs[D_SUB] = { x0.x, x0.y, x0.z, x0.w, x1.x, x1.y, x1.z, x1.w,
                        x2.x, x2.y, x2.z, x2.w, x3.x, x3.y, x3.z, x3.w };

    // xnorm: numpy strided reduction (sequential d, separate mul/add)
    float xn = 0.f;
#pragma unroll
    for (int d = 0; d < D_SUB; d++)
        xn = __fadd_rn(xn, __fmul_rn(xs[d], xs[d]));

    v2f xs2[D_SUB];
#pragma unroll
    for (int d = 0; d < D_SUB; d++) xs2[d] = (v2f){xs[d], xs[d]};
    const v2f xnv  = (v2f){xn, xn};
    const v2f twov = (v2f){2.f, 2.f};

    int bestk = 0;
    bool done = false;
    while (true) {
        unsigned long long todo = __ballot(!done);
        if (!todo) break;
        int src  = (int)(__ffsll((long long)todo) - 1);
        int lcur = __builtin_amdgcn_readlane(l, src);      // uniform label for this pass

        const float* cbs = cb       + ((size_t)(lcur * N_SUB + s) << 12);  // [d][k] row -> s_load
        const float* cns = cnorm_cb + ((size_t)(lcur * N_SUB + s) << 8);   // uniform -> s_load

        float bx = 1e30f, by = 1e30f;
        int   kx = 0, ky = 0;
        {
#pragma clang fp contract(off)
#pragma unroll 4
            for (int kkp = 0; kkp < N_CLUSTERS / 2; kkp++) {
                v2f cn2 = *(const v2f*)(cns + (kkp << 1));
                v2f a = (v2f){0.f, 0.f};
#pragma unroll
                for (int d = 0; d < D_SUB; d++) {
                    v2f c = *(const v2f*)(cbs + (size_t)(d * N_CLUSTERS) + (kkp << 1));
                    a = a + xs2[d] * c;          // v_pk_mul + v_pk_add, exact order
                }
                v2f dd = (xnv - twov * a) + cn2;
                if (dd.x < bx) { bx = dd.x; kx = kkp; }
                if (dd.y < by) { by = dd.y; ky = kkp; }
            }
        }
        // merge even/odd chains: strictly-better or equal-with-lower-k picks odd
        int bk = 2 * kx;
        { int kodd = 2 * ky + 1; if (by < bx || (by == bx && kodd < bk)) bk = kodd; }

        if (!done && l == lcur) { bestk = bk; done = true; }
    }
    codes[((size_t)n << 3) | s] = (unsigned char)bestk;
}

// ---------------------------------------------------------------- decode (fast): 1 line per (n,s)
__global__ __launch_bounds__(256) void pq_decode_fast(
    const float* __restrict__ cbT2, const int* __restrict__ labels,
    const unsigned char* __restrict__ codes, float* __restrict__ out)
{
    int s = blockIdx.x & 7;
    int n = (blockIdx.x >> 3) * 256 + threadIdx.x;
    int l = labels[n];
    int k = codes[(size_t)n * N_SUB + s];
    const float4* p = (const float4*)(cbT2 + ((size_t)(l * N_SUB + s) << 12) + ((size_t)k << 4));
    float4 a = p[0], b = p[1], c = p[2], d = p[3];
    float v[D_SUB] = { a.x, a.y, a.z, a.w, b.x, b.y, b.z, b.w,
                       c.x, c.y, c.z, c.w, d.x, d.y, d.z, d.w };
#pragma unroll
    for (int dd = 0; dd < D_SUB; dd++)
        out[(size_t)(s * D_SUB + dd) * N_DATA + n] = v[dd];   // coalesced
}

// ---------------------------------------------------------------- decode (fallback): strided column gather
__global__ __launch_bounds__(256) void pq_decode(
    const float* __restrict__ cb, const int* __restrict__ labels,
    const unsigned char* __restrict__ codes, float* __restrict__ out)
{
    int s = blockIdx.x & 7;
    int n = (blockIdx.x >> 3) * 256 + threadIdx.x;
    int l = labels[n];
    int k = codes[(size_t)n * N_SUB + s];
    const float* base = cb + ((size_t)(l * N_SUB + s) * D_SUB) * N_CLUSTERS + k;
#pragma unroll
    for (int dd = 0; dd < D_SUB; dd++)
        out[(size_t)(s * D_SUB + dd) * N_DATA + n] = base[(size_t)dd * N_CLUSTERS];
}

// ---------------------------------------------------------------- launcher
extern "C" void kernel_launch(void* const* d_in, const int* in_sizes, int n_in,
                              void* d_out, int out_size, void* d_ws, size_t ws_size,
                              hipStream_t stream)
{
    (void)in_sizes; (void)n_in; (void)out_size;
    const float* x   = (const float*)d_in[0];
    const float* cb  = (const float*)d_in[1];
    const float* sel = (const float*)d_in[2];
    float* out = (float*)d_out;

    int*   wsi    = (int*)d_ws;
    float* wsf    = (float*)d_ws;
    int*   labels = wsi + WS_LABELS;
    unsigned int* perm = (unsigned int*)(wsi + WS_PERM);
    int*   cnt    = wsi + WS_CNT;
    int*   claim  = wsi + WS_CLAIM;
    float* cnorm  = wsf + WS_CNORM;
    float* cnsel  = wsf + WS_CNSEL;
    unsigned char* codes = (unsigned char*)(wsi + WS_CODES);

    // row-major decode codebook only if the workspace is big enough (~10.5 MiB)
    bool big = ws_size >= (size_t)(WS_CBT2 + CBT2_WORDS) * 4u;
    float* cbT2 = big ? (wsf + WS_CBT2) : (float*)nullptr;

    // permuted-gathered x (64 MiB) lives in d_out; decode overwrites it fully
    float* xg = out;

    hipLaunchKernelGGL(pq_precompute, dim3(512), dim3(256), 0, stream, cb, sel, cnorm, cnsel, cbT2, cnt, claim);
    hipLaunchKernelGGL(pq_labels2, dim3(N_DATA / 256), dim3(256), 0, stream, x, sel, cnsel, labels, cnt);
    hipLaunchKernelGGL(pq_scatter, dim3(N_DATA / 1024), dim3(256), 0, stream, x, labels, cnt, claim, perm, xg);
    hipLaunchKernelGGL(pq_encode9, dim3((N_DATA / 256) * N_SUB), dim3(256), 0, stream,
                       xg, cb, cnorm, perm, codes);
    if (big)
        hipLaunchKernelGGL(pq_decode_fast, dim3((N_DATA / 256) * N_SUB), dim3(256), 0, stream,
                           cbT2, labels, codes, out);
    else
        hipLaunchKernelGGL(pq_decode, dim3((N_DATA / 256) * N_SUB), dim3(256), 0, stream,
                           cb, labels, codes, out);
}